// Round 4
// baseline (299.847 us; speedup 1.0000x reference)
//
#include <hip/hip_runtime.h>

typedef __bf16 bf16x8 __attribute__((ext_vector_type(8)));
typedef float  f32x4  __attribute__((ext_vector_type(4)));

#define AS1 __attribute__((address_space(1)))
#define AS3 __attribute__((address_space(3)))

__device__ __forceinline__ float bf2f(ushort u) {
    union { unsigned int i; float f; } v; v.i = ((unsigned int)u) << 16; return v.f;
}
__device__ __forceinline__ ushort f2bf(float f) {
    union { float f; unsigned int i; } v; v.f = f;
    unsigned int i = v.i;
    unsigned int r = i + 0x7FFFu + ((i >> 16) & 1u);   // RNE
    return (ushort)(r >> 16);
}
__device__ __forceinline__ float bflo(unsigned int u) { return bf2f((ushort)(u & 0xFFFFu)); }
__device__ __forceinline__ float bfhi(unsigned int u) { return bf2f((ushort)(u >> 16)); }

// wave-level inline dtype sniff: all 64 lanes agree; 1 = bf16 inputs, 0 = f32
__device__ __forceinline__ bool sniff_inline(const ushort* __restrict__ x) {
    const int lane = threadIdx.x & 63;
    int cnt = 0;
    #pragma unroll
    for (int r = 0; r < 4; r++) {
        const ushort u = x[lane + r * 64];
        const int e = (u >> 7) & 0xFF;
        if ((u & 0x7FFF) == 0 || (e >= 112 && e <= 141)) cnt++;
    }
    #pragma unroll
    for (int o = 32; o > 0; o >>= 1) cnt += __shfl_xor(cnt, o);
    return cnt >= 224;
}

// ---------------------------------------------------------------------------
// canonicalize all inputs into packed bf16 region; also writes xpw_pad [64,512]
// (rows 48..63 zero).  Inline sniff — no separate flag kernel.
// ---------------------------------------------------------------------------
struct CanonArgs {
    const void* src[20];
    int off[20];
    int total;
};

__launch_bounds__(256)
__global__ void canon_k(CanonArgs a, ushort* __restrict__ dst, ushort* __restrict__ xpw_pad,
                        const ushort* __restrict__ sniffx)
{
    const int i = blockIdx.x * 256 + threadIdx.x;
    if (i >= a.total) {
        const int j = i - a.total;
        if (j < 8192) xpw_pad[24576 + j] = 0;   // pad rows 48..63
        return;
    }
    const bool fl = sniff_inline(sniffx);
    int s = 0;
    #pragma unroll
    for (int t = 1; t < 20; t++) if (i >= a.off[t]) s = t;
    const int li = i - a.off[s];
    ushort v;
    if (fl) v = ((const ushort*)a.src[s])[li];
    else    v = f2bf(((const float*)a.src[s])[li]);
    dst[i] = v;
    if (s == 5) xpw_pad[li] = v;                // xpw rows 0..47
}

// ---------------------------------------------------------------------------
// GEMM: C[M,N] = act(A[M,K](bf16,lda) @ W[N,K]^T(bf16) + bias[N])
// ACT: 0 none, 1 gelu
// ---------------------------------------------------------------------------
template<int BM, int BN, int ACT, bool HASB, bool WF32, bool WBF16>
__launch_bounds__(256, 2)
__global__ void gemm_bt(const ushort* __restrict__ A, const ushort* __restrict__ W,
                        const ushort* __restrict__ bias,
                        float* __restrict__ Cf, ushort* __restrict__ Cb,
                        int M, int N, int K, int lda)
{
    constexpr int WMT = BM / 32;
    constexpr int WNT = BN / 32;
    __shared__ __align__(16) ushort As[BM * 32];
    __shared__ __align__(16) ushort Bs[BN * 32];
    const int tid  = threadIdx.x;
    const int wave = tid >> 6;
    const int lane = tid & 63;
    const int m0 = blockIdx.x * BM;
    const int n0 = blockIdx.y * BN;
    const int wm = (wave >> 1) * (BM / 2);
    const int wn = (wave & 1) * (BN / 2);
    const int lrow = lane & 15;
    const int quad = lane >> 4;

    f32x4 acc[WMT][WNT];
    #pragma unroll
    for (int i = 0; i < WMT; i++)
        #pragma unroll
        for (int j = 0; j < WNT; j++)
            #pragma unroll
            for (int r = 0; r < 4; r++) acc[i][j][r] = 0.f;

    for (int k0 = 0; k0 < K; k0 += 32) {
        #pragma unroll
        for (int t = 0; t < BM / 64; t++) {
            const int inst = t * 4 + wave;
            const int row  = inst * 16 + (lane >> 2);
            const int sub  = lane & 3;
            const ushort* gp = A + (size_t)(m0 + row) * lda + (k0 + sub * 8);
            __builtin_amdgcn_global_load_lds((AS1 void*)(void*)gp,
                                             (AS3 void*)(As + inst * 512), 16, 0, 0);
        }
        #pragma unroll
        for (int t = 0; t < BN / 64; t++) {
            const int inst = t * 4 + wave;
            const int row  = inst * 16 + (lane >> 2);
            const int sub  = lane & 3;
            const ushort* gp = W + (size_t)(n0 + row) * K + (k0 + sub * 8);
            __builtin_amdgcn_global_load_lds((AS1 void*)(void*)gp,
                                             (AS3 void*)(Bs + inst * 512), 16, 0, 0);
        }
        __syncthreads();

        bf16x8 afr[WMT], bfr[WNT];
        #pragma unroll
        for (int i = 0; i < WMT; i++)
            afr[i] = *(const bf16x8*)&As[(wm + i * 16 + lrow) * 32 + quad * 8];
        #pragma unroll
        for (int j = 0; j < WNT; j++)
            bfr[j] = *(const bf16x8*)&Bs[(wn + j * 16 + lrow) * 32 + quad * 8];
        #pragma unroll
        for (int i = 0; i < WMT; i++)
            #pragma unroll
            for (int j = 0; j < WNT; j++)
                acc[i][j] = __builtin_amdgcn_mfma_f32_16x16x32_bf16(afr[i], bfr[j], acc[i][j], 0, 0, 0);
        __syncthreads();
    }

    // C/D layout: col(n)=lane&15, row(m)=quad*4+reg
    #pragma unroll
    for (int i = 0; i < WMT; i++) {
        const int gm = m0 + wm + i * 16 + quad * 4;
        #pragma unroll
        for (int j = 0; j < WNT; j++) {
            const int gn = n0 + wn + j * 16 + lrow;
            const float bv = HASB ? bf2f(bias[gn]) : 0.f;
            #pragma unroll
            for (int r = 0; r < 4; r++) {
                float v = acc[i][j][r] + bv;
                if (ACT == 1) v = 0.5f * v * (1.f + erff(v * 0.70710678118654752f));
                const size_t off = (size_t)(gm + r) * N + gn;
                if (WF32)  Cf[off] = v;
                if (WBF16) Cb[off] = f2bf(v);
            }
        }
    }
}

// ---------------------------------------------------------------------------
// fused GEMM (M=8192, N=256, BM=64, BN=256, grid 128) + row LayerNorm epilogue
// MODE 0 (out_proj+ln1): resid = x (flag dtype), writes y1f (f32) + y1b (bf16)
// MODE 1 (fc2+gelu+ln2): resid = y1f (f32),     writes d_out (flag dtype)
// ---------------------------------------------------------------------------
template<int ACT, int MODE>
__launch_bounds__(256, 2)
__global__ void gemm_ln(const ushort* __restrict__ A, const ushort* __restrict__ W,
                        const ushort* __restrict__ bias,
                        const void* __restrict__ resid, const ushort* __restrict__ sniffx,
                        const ushort* __restrict__ g, const ushort* __restrict__ bvec,
                        float* __restrict__ y1f_out, ushort* __restrict__ y1b_out,
                        void* __restrict__ dout, int K)
{
    __shared__ __align__(16) ushort As[64 * 32];
    __shared__ __align__(16) ushort Bs[256 * 32];
    __shared__ float redS[128], redQ[128];
    const int tid  = threadIdx.x;
    const int wave = tid >> 6;
    const int lane = tid & 63;
    const int m0 = blockIdx.x * 64;
    const int wm = (wave >> 1) * 32;
    const int wn = (wave & 1) * 128;
    const int lrow = lane & 15;
    const int quad = lane >> 4;

    f32x4 acc[2][8];
    #pragma unroll
    for (int i = 0; i < 2; i++)
        #pragma unroll
        for (int j = 0; j < 8; j++)
            #pragma unroll
            for (int r = 0; r < 4; r++) acc[i][j][r] = 0.f;

    for (int k0 = 0; k0 < K; k0 += 32) {
        {
            const int row = wave * 16 + (lane >> 2);
            const int sub = lane & 3;
            const ushort* gp = A + (size_t)(m0 + row) * K + (k0 + sub * 8);
            __builtin_amdgcn_global_load_lds((AS1 void*)(void*)gp,
                                             (AS3 void*)(As + wave * 512), 16, 0, 0);
        }
        #pragma unroll
        for (int t = 0; t < 4; t++) {
            const int inst = t * 4 + wave;
            const int row  = inst * 16 + (lane >> 2);
            const int sub  = lane & 3;
            const ushort* gp = W + (size_t)row * K + (k0 + sub * 8);
            __builtin_amdgcn_global_load_lds((AS1 void*)(void*)gp,
                                             (AS3 void*)(Bs + inst * 512), 16, 0, 0);
        }
        __syncthreads();

        bf16x8 afr[2], bfr[8];
        #pragma unroll
        for (int i = 0; i < 2; i++)
            afr[i] = *(const bf16x8*)&As[(wm + i * 16 + lrow) * 32 + quad * 8];
        #pragma unroll
        for (int j = 0; j < 8; j++)
            bfr[j] = *(const bf16x8*)&Bs[(wn + j * 16 + lrow) * 32 + quad * 8];
        #pragma unroll
        for (int i = 0; i < 2; i++)
            #pragma unroll
            for (int j = 0; j < 8; j++)
                acc[i][j] = __builtin_amdgcn_mfma_f32_16x16x32_bf16(afr[i], bfr[j], acc[i][j], 0, 0, 0);
        __syncthreads();
    }

    const bool fl = sniff_inline(sniffx);
    float bv[8];
    #pragma unroll
    for (int j = 0; j < 8; j++) bv[j] = bf2f(bias[wn + j * 16 + lrow]);

    float ps[2][4], pq[2][4];
    #pragma unroll
    for (int i = 0; i < 2; i++)
        #pragma unroll
        for (int r = 0; r < 4; r++) { ps[i][r] = 0.f; pq[i][r] = 0.f; }

    #pragma unroll
    for (int i = 0; i < 2; i++) {
        const int gm = m0 + wm + i * 16 + quad * 4;
        #pragma unroll
        for (int j = 0; j < 8; j++) {
            const int col = wn + j * 16 + lrow;
            #pragma unroll
            for (int r = 0; r < 4; r++) {
                const size_t off = (size_t)(gm + r) * 256 + col;
                float v = acc[i][j][r] + bv[j];
                if (ACT == 1) v = 0.5f * v * (1.f + erff(v * 0.70710678118654752f));
                float rv;
                if (MODE == 0) rv = fl ? bf2f(((const ushort*)resid)[off])
                                       : ((const float*)resid)[off];
                else           rv = ((const float*)resid)[off];
                v += rv;
                acc[i][j][r] = v;
                ps[i][r] += v;
                pq[i][r] += v * v;
            }
        }
    }
    #pragma unroll
    for (int i = 0; i < 2; i++)
        #pragma unroll
        for (int r = 0; r < 4; r++) {
            float s = ps[i][r], q = pq[i][r];
            #pragma unroll
            for (int o = 8; o > 0; o >>= 1) { s += __shfl_xor(s, o); q += __shfl_xor(q, o); }
            if (lrow == 0) {
                const int lr = wm + i * 16 + quad * 4 + r;
                redS[(wave & 1) * 64 + lr] = s;
                redQ[(wave & 1) * 64 + lr] = q;
            }
        }
    __syncthreads();

    float gf[8], bf2v[8];
    #pragma unroll
    for (int j = 0; j < 8; j++) {
        const int col = wn + j * 16 + lrow;
        gf[j]   = bf2f(g[col]);
        bf2v[j] = bf2f(bvec[col]);
    }
    #pragma unroll
    for (int i = 0; i < 2; i++) {
        const int gm = m0 + wm + i * 16 + quad * 4;
        #pragma unroll
        for (int r = 0; r < 4; r++) {
            const int lr = wm + i * 16 + quad * 4 + r;
            const float S = redS[lr] + redS[64 + lr];
            const float Q = redQ[lr] + redQ[64 + lr];
            const float mean = S * (1.f / 256.f);
            const float var  = Q * (1.f / 256.f) - mean * mean;
            const float rs   = rsqrtf(var + 1e-5f);
            #pragma unroll
            for (int j = 0; j < 8; j++) {
                const int col = wn + j * 16 + lrow;
                const size_t off = (size_t)(gm + r) * 256 + col;
                const float out = (acc[i][j][r] - mean) * rs * gf[j] + bf2v[j];
                if (MODE == 0) {
                    y1f_out[off] = out;
                    y1b_out[off] = f2bf(out);
                } else {
                    if (fl) ((ushort*)dout)[off] = f2bf(out);
                    else    ((float*)dout)[off]  = out;
                }
            }
        }
    }
}

// ---------------------------------------------------------------------------
// depthwise causal conv (DC=4) + SiLU, 8 d's per thread, uint4 loads
// ---------------------------------------------------------------------------
__launch_bounds__(256)
__global__ void conv_silu_k(const ushort* __restrict__ xz, const ushort* __restrict__ cw,
                            const ushort* __restrict__ cb, ushort* __restrict__ xc)
{
    const int idx = blockIdx.x * 256 + threadIdx.x;   // [0, 8192*64)
    const int t  = idx >> 6;
    const int d8 = (idx & 63) * 8;
    const int l  = t & 2047;

    ushort wl[32];
    *(uint4*)&wl[0]  = *(const uint4*)&cw[d8 * 4];
    *(uint4*)&wl[8]  = *(const uint4*)&cw[d8 * 4 + 8];
    *(uint4*)&wl[16] = *(const uint4*)&cw[d8 * 4 + 16];
    *(uint4*)&wl[24] = *(const uint4*)&cw[d8 * 4 + 24];

    ushort bl[8];
    *(uint4*)&bl[0] = *(const uint4*)&cb[d8];

    float acc[8];
    #pragma unroll
    for (int j = 0; j < 8; j++) acc[j] = bf2f(bl[j]);

    #pragma unroll
    for (int k = 0; k < 4; k++) {
        const int ls = l - 3 + k;
        if (ls >= 0) {
            ushort xl[8];
            *(uint4*)&xl[0] = *(const uint4*)&xz[(size_t)(t - 3 + k) * 1024 + d8];
            #pragma unroll
            for (int j = 0; j < 8; j++) acc[j] += bf2f(xl[j]) * bf2f(wl[j * 4 + k]);
        }
    }
    ushort ol[8];
    #pragma unroll
    for (int j = 0; j < 8; j++) {
        const float s = acc[j] / (1.f + __expf(-acc[j]));
        ol[j] = f2bf(s);
    }
    *(uint4*)&xc[(size_t)idx * 8] = *(uint4*)&ol[0];
}

// ---------------------------------------------------------------------------
// chunked scan, 64 chunks x 32 steps; dt computed inline from xdbl[:, :16]
// grid (2 dblk, 64 chunk, 4 b), 256 thr
// ---------------------------------------------------------------------------
__launch_bounds__(256)
__global__ void scan1_k(const float* __restrict__ xdbl, const ushort* __restrict__ xc,
                        const ushort* __restrict__ dtw, const ushort* __restrict__ dtb,
                        const ushort* __restrict__ Alog, float* __restrict__ summ)
{
    __shared__ float XD[32 * 32];   // [step][col 0..31]: 0..15 dt-dot, 16..31 B
    const int tid = threadIdx.x;
    const int c = blockIdx.y, b = blockIdx.z;
    const int t0 = b * 2048 + c * 32;
    for (int e = tid; e < 1024; e += 256)
        XD[e] = xdbl[(size_t)(t0 + (e >> 5)) * 64 + (e & 31)];
    __syncthreads();
    const int d = blockIdx.x * 256 + tid;

    const uint4 w0 = *(const uint4*)&dtw[d * 16];
    const uint4 w1 = *(const uint4*)&dtw[d * 16 + 8];
    const float wd[16] = { bflo(w0.x), bfhi(w0.x), bflo(w0.y), bfhi(w0.y),
                           bflo(w0.z), bfhi(w0.z), bflo(w0.w), bfhi(w0.w),
                           bflo(w1.x), bfhi(w1.x), bflo(w1.y), bfhi(w1.y),
                           bflo(w1.z), bfhi(w1.z), bflo(w1.w), bfhi(w1.w) };
    const float dtbv = bf2f(dtb[d]);

    float A[16], h[16];
    #pragma unroll
    for (int n = 0; n < 16; n++) {
        A[n] = -__expf(bf2f(Alog[d * 16 + n]));
        h[n] = 0.f;
    }
    float sdt = 0.f;
    for (int i = 0; i < 32; i++) {
        const int t = t0 + i;
        const float* Xr = &XD[i * 32];
        float s = dtbv;
        #pragma unroll
        for (int k = 0; k < 16; k++) s += Xr[k] * wd[k];
        const float dtv = (s > 15.f) ? s : __logf(1.f + __expf(s));
        const float xiv = bf2f(xc[(size_t)t * 512 + d]);
        const float dx = dtv * xiv;
        sdt += dtv;
        #pragma unroll
        for (int n = 0; n < 16; n++) {
            const float da = __expf(dtv * A[n]);
            h[n] = da * h[n] + dx * Xr[16 + n];
        }
    }
    const size_t base = ((size_t)(b * 64 + c) * 32) * 512 + d;
    #pragma unroll
    for (int n = 0; n < 16; n++) summ[base + (size_t)n * 512] = __expf(A[n] * sdt);
    #pragma unroll
    for (int n = 0; n < 16; n++) summ[base + (size_t)(16 + n) * 512] = h[n];
}

// sequential combine over 64 chunks; overwrites p-slot with h_in (in-place)
__launch_bounds__(512)
__global__ void combine_k(float* __restrict__ summ)
{
    const int b = blockIdx.x >> 4, n = blockIdx.x & 15;
    const int d = threadIdx.x;
    float h = 0.f;
    for (int c = 0; c < 64; c++) {
        const size_t sb = ((size_t)((b * 64 + c) * 32 + n)) * 512 + d;
        const float p  = summ[sb];
        const float hl = summ[sb + 8192];
        summ[sb] = h;
        h = p * h + hl;
    }
}

// pass2: replay chunk from h_in; dt inline; writes y in-place over xc
__launch_bounds__(256)
__global__ void scan2_k(const float* __restrict__ xdbl, ushort* xc,
                        const ushort* __restrict__ dtw, const ushort* __restrict__ dtb,
                        const ushort* __restrict__ Alog, const float* __restrict__ summ,
                        const ushort* __restrict__ xz, const ushort* __restrict__ Dssm)
{
    __shared__ float XD[32 * 48];   // [step][col 0..47]: 0..15 dt, 16..31 B, 32..47 C
    const int tid = threadIdx.x;
    const int c = blockIdx.y, b = blockIdx.z;
    const int t0 = b * 2048 + c * 32;
    for (int e = tid; e < 1536; e += 256)
        XD[e] = xdbl[(size_t)(t0 + (e / 48)) * 64 + (e % 48)];
    __syncthreads();
    const int d = blockIdx.x * 256 + tid;

    const uint4 w0 = *(const uint4*)&dtw[d * 16];
    const uint4 w1 = *(const uint4*)&dtw[d * 16 + 8];
    const float wd[16] = { bflo(w0.x), bfhi(w0.x), bflo(w0.y), bfhi(w0.y),
                           bflo(w0.z), bfhi(w0.z), bflo(w0.w), bfhi(w0.w),
                           bflo(w1.x), bfhi(w1.x), bflo(w1.y), bfhi(w1.y),
                           bflo(w1.z), bfhi(w1.z), bflo(w1.w), bfhi(w1.w) };
    const float dtbv = bf2f(dtb[d]);

    float A[16], h[16];
    #pragma unroll
    for (int n = 0; n < 16; n++) A[n] = -__expf(bf2f(Alog[d * 16 + n]));
    const size_t base = ((size_t)(b * 64 + c) * 32) * 512 + d;
    #pragma unroll
    for (int n = 0; n < 16; n++) h[n] = summ[base + (size_t)n * 512];
    const float Dv = bf2f(Dssm[d]);

    for (int i = 0; i < 32; i++) {
        const int t = t0 + i;
        const float* Xr = &XD[i * 48];
        float s = dtbv;
        #pragma unroll
        for (int k = 0; k < 16; k++) s += Xr[k] * wd[k];
        const float dtv = (s > 15.f) ? s : __logf(1.f + __expf(s));
        const float xiv = bf2f(xc[(size_t)t * 512 + d]);
        const float dx = dtv * xiv;
        float yv = 0.f;
        #pragma unroll
        for (int n = 0; n < 16; n++) {
            const float da = __expf(dtv * A[n]);
            h[n] = da * h[n] + dx * Xr[16 + n];
            yv += h[n] * Xr[32 + n];
        }
        yv += xiv * Dv;
        const float zv = bf2f(xz[(size_t)t * 1024 + 512 + d]);
        yv *= zv / (1.f + __expf(-zv));
        xc[(size_t)t * 512 + d] = f2bf(yv);   // yb in-place
    }
}

// ---------------------------------------------------------------------------
extern "C" void kernel_launch(void* const* d_in, const int* in_sizes, int n_in,
                              void* d_out, int out_size, void* d_ws, size_t ws_size,
                              hipStream_t stream)
{
    char* ws = (char*)d_ws;
    ushort* canon = (ushort*)(ws + 256);

    static const int coff[20] = {
        0,        2097152,  2359296,  2360320,  2362368,
        2362880,  2387456,  2395648,  2396160,  2404352,
        2404864,  2535936,  2536192,  2536448,  2536704,
        2798848,  2799872,  3062016,  3062272,  3062528 };
    static const int ctot = 3062784;

    CanonArgs ca;
    for (int i = 0; i < 20; i++) { ca.src[i] = d_in[i]; ca.off[i] = coff[i]; }
    ca.total = ctot;

    const ushort* cx   = canon + coff[0];
    const ushort* cipw = canon + coff[1];
    const ushort* cipb = canon + coff[2];
    const ushort* ccw  = canon + coff[3];
    const ushort* ccb  = canon + coff[4];
    const ushort* cdtw = canon + coff[6];
    const ushort* cdtb = canon + coff[7];
    const ushort* calog= canon + coff[8];
    const ushort* cdssm= canon + coff[9];
    const ushort* copw = canon + coff[10];
    const ushort* copb = canon + coff[11];
    const ushort* cln1g= canon + coff[12];
    const ushort* cln1b= canon + coff[13];
    const ushort* cf1w = canon + coff[14];
    const ushort* cf1b = canon + coff[15];
    const ushort* cf2w = canon + coff[16];
    const ushort* cf2b = canon + coff[17];
    const ushort* cln2g= canon + coff[18];
    const ushort* cln2b= canon + coff[19];

    ushort* xpw_pad = (ushort*)(ws + 6291456);  // [64,512] bf16
    ushort* xz      = (ushort*)(ws + 8388608);  // [8192,1024] bf16, 16 MB
    ushort* xc      = (ushort*)(ws + 25165824); // [8192,512] bf16 (yb in-place later)
    float*  xdbl_f  = (float*)(ws + 33554432);  // [8192,64] f32, 2 MB
    float*  summ    = (float*)(ws + 35651584);  // [4,64,32,512] f32, 16 MB
    float*  y1f     = (float*)(ws + 52428800);  // [8192,256] f32, 8 MB
    ushort* y1b     = (ushort*)(ws + 60817408); // [8192,256] bf16, 4 MB
    ushort* f1      = (ushort*)(ws + 65011712); // [8192,1024] bf16, 16 MB
    ushort* yb      = xc;
    const ushort* sx = (const ushort*)d_in[0];

    // 1. canon + xpw padding (inline sniff)
    canon_k<<<(ctot + 8192 + 255) / 256, 256, 0, stream>>>(ca, canon, xpw_pad, sx);
    // 2. in_proj: xz = x @ ipw^T + ipb
    gemm_bt<128, 128, 0, true, false, true><<<dim3(64, 8), 256, 0, stream>>>(
        cx, cipw, cipb, nullptr, xz, 8192, 1024, 256, 256);
    // 3. conv + silu -> xc
    conv_silu_k<<<2048, 256, 0, stream>>>(xz, ccw, ccb, xc);
    // 4. xdbl = xc @ xpw_pad^T  [8192,64] f32
    gemm_bt<64, 64, 0, false, true, false><<<dim3(128, 1), 256, 0, stream>>>(
        xc, xpw_pad, nullptr, xdbl_f, nullptr, 8192, 64, 512, 512);
    // 5-7. chunked scan (dt inline)
    scan1_k<<<dim3(2, 64, 4), 256, 0, stream>>>(xdbl_f, xc, cdtw, cdtb, calog, summ);
    combine_k<<<64, 512, 0, stream>>>(summ);
    scan2_k<<<dim3(2, 64, 4), 256, 0, stream>>>(xdbl_f, xc, cdtw, cdtb, calog, summ, xz, cdssm);
    // 8. out_proj + LN1 fused -> y1f, y1b
    gemm_ln<0, 0><<<128, 256, 0, stream>>>(
        yb, copw, copb, d_in[0], sx, cln1g, cln1b, y1f, y1b, nullptr, 512);
    // 9. fc1 + gelu -> f1
    gemm_bt<128, 128, 1, true, false, true><<<dim3(64, 8), 256, 0, stream>>>(
        y1b, cf1w, cf1b, nullptr, f1, 8192, 1024, 256, 256);
    // 10. fc2 + gelu + LN2 fused -> d_out
    gemm_ln<1, 1><<<128, 256, 0, stream>>>(
        f1, cf2w, cf2b, y1f, sx, cln2g, cln2b, nullptr, nullptr, d_out, 1024);
}

// Round 5
// 271.601 us; speedup vs baseline: 1.1040x; 1.1040x over previous
//
#include <hip/hip_runtime.h>

typedef __bf16 bf16x8 __attribute__((ext_vector_type(8)));
typedef float  f32x4  __attribute__((ext_vector_type(4)));

#define AS1 __attribute__((address_space(1)))
#define AS3 __attribute__((address_space(3)))

__device__ __forceinline__ float bf2f(ushort u) {
    union { unsigned int i; float f; } v; v.i = ((unsigned int)u) << 16; return v.f;
}
__device__ __forceinline__ ushort f2bf(float f) {
    union { float f; unsigned int i; } v; v.f = f;
    unsigned int i = v.i;
    unsigned int r = i + 0x7FFFu + ((i >> 16) & 1u);   // RNE
    return (ushort)(r >> 16);
}
__device__ __forceinline__ float bflo(unsigned int u) { return bf2f((ushort)(u & 0xFFFFu)); }
__device__ __forceinline__ float bfhi(unsigned int u) { return bf2f((ushort)(u >> 16)); }

// wave-level inline dtype sniff: all 64 lanes agree; 1 = bf16 inputs, 0 = f32
__device__ __forceinline__ bool sniff_inline(const ushort* __restrict__ x) {
    const int lane = threadIdx.x & 63;
    int cnt = 0;
    #pragma unroll
    for (int r = 0; r < 4; r++) {
        const ushort u = x[lane + r * 64];
        const int e = (u >> 7) & 0xFF;
        if ((u & 0x7FFF) == 0 || (e >= 112 && e <= 141)) cnt++;
    }
    #pragma unroll
    for (int o = 32; o > 0; o >>= 1) cnt += __shfl_xor(cnt, o);
    return cnt >= 224;
}

// ---------------------------------------------------------------------------
// canonicalize all inputs into packed bf16 region; also writes xpw_pad [64,512]
// ---------------------------------------------------------------------------
struct CanonArgs {
    const void* src[20];
    int off[20];
    int total;
};

__launch_bounds__(256)
__global__ void canon_k(CanonArgs a, ushort* __restrict__ dst, ushort* __restrict__ xpw_pad,
                        const ushort* __restrict__ sniffx)
{
    const int i = blockIdx.x * 256 + threadIdx.x;
    if (i >= a.total) {
        const int j = i - a.total;
        if (j < 8192) xpw_pad[24576 + j] = 0;   // pad rows 48..63
        return;
    }
    const bool fl = sniff_inline(sniffx);
    int s = 0;
    #pragma unroll
    for (int t = 1; t < 20; t++) if (i >= a.off[t]) s = t;
    const int li = i - a.off[s];
    ushort v;
    if (fl) v = ((const ushort*)a.src[s])[li];
    else    v = f2bf(((const float*)a.src[s])[li]);
    dst[i] = v;
    if (s == 5) xpw_pad[li] = v;                // xpw rows 0..47
}

// ---------------------------------------------------------------------------
// GEMM: C[M,N] = act(A[M,K](bf16,lda) @ W[N,K]^T(bf16) + bias[N])
// ACT: 0 none, 1 gelu
// ---------------------------------------------------------------------------
template<int BM, int BN, int ACT, bool HASB, bool WF32, bool WBF16>
__launch_bounds__(256, 2)
__global__ void gemm_bt(const ushort* __restrict__ A, const ushort* __restrict__ W,
                        const ushort* __restrict__ bias,
                        float* __restrict__ Cf, ushort* __restrict__ Cb,
                        int M, int N, int K, int lda)
{
    constexpr int WMT = BM / 32;
    constexpr int WNT = BN / 32;
    __shared__ __align__(16) ushort As[BM * 32];
    __shared__ __align__(16) ushort Bs[BN * 32];
    const int tid  = threadIdx.x;
    const int wave = tid >> 6;
    const int lane = tid & 63;
    const int m0 = blockIdx.x * BM;
    const int n0 = blockIdx.y * BN;
    const int wm = (wave >> 1) * (BM / 2);
    const int wn = (wave & 1) * (BN / 2);
    const int lrow = lane & 15;
    const int quad = lane >> 4;

    f32x4 acc[WMT][WNT];
    #pragma unroll
    for (int i = 0; i < WMT; i++)
        #pragma unroll
        for (int j = 0; j < WNT; j++)
            #pragma unroll
            for (int r = 0; r < 4; r++) acc[i][j][r] = 0.f;

    for (int k0 = 0; k0 < K; k0 += 32) {
        #pragma unroll
        for (int t = 0; t < BM / 64; t++) {
            const int inst = t * 4 + wave;
            const int row  = inst * 16 + (lane >> 2);
            const int sub  = lane & 3;
            const ushort* gp = A + (size_t)(m0 + row) * lda + (k0 + sub * 8);
            __builtin_amdgcn_global_load_lds((AS1 void*)(void*)gp,
                                             (AS3 void*)(As + inst * 512), 16, 0, 0);
        }
        #pragma unroll
        for (int t = 0; t < BN / 64; t++) {
            const int inst = t * 4 + wave;
            const int row  = inst * 16 + (lane >> 2);
            const int sub  = lane & 3;
            const ushort* gp = W + (size_t)(n0 + row) * K + (k0 + sub * 8);
            __builtin_amdgcn_global_load_lds((AS1 void*)(void*)gp,
                                             (AS3 void*)(Bs + inst * 512), 16, 0, 0);
        }
        __syncthreads();

        bf16x8 afr[WMT], bfr[WNT];
        #pragma unroll
        for (int i = 0; i < WMT; i++)
            afr[i] = *(const bf16x8*)&As[(wm + i * 16 + lrow) * 32 + quad * 8];
        #pragma unroll
        for (int j = 0; j < WNT; j++)
            bfr[j] = *(const bf16x8*)&Bs[(wn + j * 16 + lrow) * 32 + quad * 8];
        #pragma unroll
        for (int i = 0; i < WMT; i++)
            #pragma unroll
            for (int j = 0; j < WNT; j++)
                acc[i][j] = __builtin_amdgcn_mfma_f32_16x16x32_bf16(afr[i], bfr[j], acc[i][j], 0, 0, 0);
        __syncthreads();
    }

    // C/D layout: col(n)=lane&15, row(m)=quad*4+reg
    #pragma unroll
    for (int i = 0; i < WMT; i++) {
        const int gm = m0 + wm + i * 16 + quad * 4;
        #pragma unroll
        for (int j = 0; j < WNT; j++) {
            const int gn = n0 + wn + j * 16 + lrow;
            const float bv = HASB ? bf2f(bias[gn]) : 0.f;
            #pragma unroll
            for (int r = 0; r < 4; r++) {
                float v = acc[i][j][r] + bv;
                if (ACT == 1) v = 0.5f * v * (1.f + erff(v * 0.70710678118654752f));
                const size_t off = (size_t)(gm + r) * N + gn;
                if (WF32)  Cf[off] = v;
                if (WBF16) Cb[off] = f2bf(v);
            }
        }
    }
}

// ---------------------------------------------------------------------------
// xdbl GEMM split-K: [8192,64] = xc[8192,512] @ xpw_pad[64,512]^T
// grid (128 M-tiles, 2 K-halves); each K-half writes its own [8192,64] buffer
// ---------------------------------------------------------------------------
__launch_bounds__(256, 2)
__global__ void xdbl_k(const ushort* __restrict__ A, const ushort* __restrict__ W,
                       float* __restrict__ Cf)
{
    __shared__ __align__(16) ushort As[64 * 32];
    __shared__ __align__(16) ushort Bs[64 * 32];
    const int tid  = threadIdx.x;
    const int wave = tid >> 6;
    const int lane = tid & 63;
    const int m0   = blockIdx.x * 64;
    const int kbeg = blockIdx.y * 256;
    const int wm = (wave >> 1) * 32;
    const int wn = (wave & 1) * 32;
    const int lrow = lane & 15;
    const int quad = lane >> 4;

    f32x4 acc[2][2];
    #pragma unroll
    for (int i = 0; i < 2; i++)
        #pragma unroll
        for (int j = 0; j < 2; j++)
            #pragma unroll
            for (int r = 0; r < 4; r++) acc[i][j][r] = 0.f;

    for (int k0 = kbeg; k0 < kbeg + 256; k0 += 32) {
        {
            const int row = wave * 16 + (lane >> 2);
            const int sub = lane & 3;
            const ushort* gp = A + (size_t)(m0 + row) * 512 + (k0 + sub * 8);
            __builtin_amdgcn_global_load_lds((AS1 void*)(void*)gp,
                                             (AS3 void*)(As + wave * 512), 16, 0, 0);
        }
        {
            const int row = wave * 16 + (lane >> 2);
            const int sub = lane & 3;
            const ushort* gp = W + (size_t)row * 512 + (k0 + sub * 8);
            __builtin_amdgcn_global_load_lds((AS1 void*)(void*)gp,
                                             (AS3 void*)(Bs + wave * 512), 16, 0, 0);
        }
        __syncthreads();
        bf16x8 afr[2], bfr[2];
        #pragma unroll
        for (int i = 0; i < 2; i++)
            afr[i] = *(const bf16x8*)&As[(wm + i * 16 + lrow) * 32 + quad * 8];
        #pragma unroll
        for (int j = 0; j < 2; j++)
            bfr[j] = *(const bf16x8*)&Bs[(wn + j * 16 + lrow) * 32 + quad * 8];
        #pragma unroll
        for (int i = 0; i < 2; i++)
            #pragma unroll
            for (int j = 0; j < 2; j++)
                acc[i][j] = __builtin_amdgcn_mfma_f32_16x16x32_bf16(afr[i], bfr[j], acc[i][j], 0, 0, 0);
        __syncthreads();
    }

    float* out = Cf + (size_t)blockIdx.y * 524288;
    #pragma unroll
    for (int i = 0; i < 2; i++) {
        const int gm = m0 + wm + i * 16 + quad * 4;
        #pragma unroll
        for (int j = 0; j < 2; j++) {
            const int gn = wn + j * 16 + lrow;
            #pragma unroll
            for (int r = 0; r < 4; r++)
                out[(size_t)(gm + r) * 64 + gn] = acc[i][j][r];
        }
    }
}

// ---------------------------------------------------------------------------
// depthwise causal conv (DC=4) + SiLU, 8 d's per thread, uint4 loads
// ---------------------------------------------------------------------------
__launch_bounds__(256)
__global__ void conv_silu_k(const ushort* __restrict__ xz, const ushort* __restrict__ cw,
                            const ushort* __restrict__ cb, ushort* __restrict__ xc)
{
    const int idx = blockIdx.x * 256 + threadIdx.x;   // [0, 8192*64)
    const int t  = idx >> 6;
    const int d8 = (idx & 63) * 8;
    const int l  = t & 2047;

    ushort wl[32];
    *(uint4*)&wl[0]  = *(const uint4*)&cw[d8 * 4];
    *(uint4*)&wl[8]  = *(const uint4*)&cw[d8 * 4 + 8];
    *(uint4*)&wl[16] = *(const uint4*)&cw[d8 * 4 + 16];
    *(uint4*)&wl[24] = *(const uint4*)&cw[d8 * 4 + 24];

    ushort bl[8];
    *(uint4*)&bl[0] = *(const uint4*)&cb[d8];

    float acc[8];
    #pragma unroll
    for (int j = 0; j < 8; j++) acc[j] = bf2f(bl[j]);

    #pragma unroll
    for (int k = 0; k < 4; k++) {
        const int ls = l - 3 + k;
        if (ls >= 0) {
            ushort xl[8];
            *(uint4*)&xl[0] = *(const uint4*)&xz[(size_t)(t - 3 + k) * 1024 + d8];
            #pragma unroll
            for (int j = 0; j < 8; j++) acc[j] += bf2f(xl[j]) * bf2f(wl[j * 4 + k]);
        }
    }
    ushort ol[8];
    #pragma unroll
    for (int j = 0; j < 8; j++) {
        const float s = acc[j] / (1.f + __expf(-acc[j]));
        ol[j] = f2bf(s);
    }
    *(uint4*)&xc[(size_t)idx * 8] = *(uint4*)&ol[0];
}

// ---------------------------------------------------------------------------
// chunked scan, 64 chunks x 32 steps; dt computed inline from xdbl[:, :16]
// xdbl arrives as two split-K halves to be summed.
// ---------------------------------------------------------------------------
__launch_bounds__(256)
__global__ void scan1_k(const float* __restrict__ xdbl, const ushort* __restrict__ xc,
                        const ushort* __restrict__ dtw, const ushort* __restrict__ dtb,
                        const ushort* __restrict__ Alog, float* __restrict__ summ)
{
    __shared__ float XD[32 * 32];   // [step][col 0..31]: 0..15 dt-dot, 16..31 B
    const int tid = threadIdx.x;
    const int c = blockIdx.y, b = blockIdx.z;
    const int t0 = b * 2048 + c * 32;
    for (int e = tid; e < 1024; e += 256) {
        const size_t idx = (size_t)(t0 + (e >> 5)) * 64 + (e & 31);
        XD[e] = xdbl[idx] + xdbl[idx + 524288];
    }
    __syncthreads();
    const int d = blockIdx.x * 256 + tid;

    const uint4 w0 = *(const uint4*)&dtw[d * 16];
    const uint4 w1 = *(const uint4*)&dtw[d * 16 + 8];
    const float wd[16] = { bflo(w0.x), bfhi(w0.x), bflo(w0.y), bfhi(w0.y),
                           bflo(w0.z), bfhi(w0.z), bflo(w0.w), bfhi(w0.w),
                           bflo(w1.x), bfhi(w1.x), bflo(w1.y), bfhi(w1.y),
                           bflo(w1.z), bfhi(w1.z), bflo(w1.w), bfhi(w1.w) };
    const float dtbv = bf2f(dtb[d]);

    float A[16], h[16];
    #pragma unroll
    for (int n = 0; n < 16; n++) {
        A[n] = -__expf(bf2f(Alog[d * 16 + n]));
        h[n] = 0.f;
    }
    float sdt = 0.f;
    for (int i = 0; i < 32; i++) {
        const int t = t0 + i;
        const float* Xr = &XD[i * 32];
        float s = dtbv;
        #pragma unroll
        for (int k = 0; k < 16; k++) s += Xr[k] * wd[k];
        const float dtv = (s > 15.f) ? s : __logf(1.f + __expf(s));
        const float xiv = bf2f(xc[(size_t)t * 512 + d]);
        const float dx = dtv * xiv;
        sdt += dtv;
        #pragma unroll
        for (int n = 0; n < 16; n++) {
            const float da = __expf(dtv * A[n]);
            h[n] = da * h[n] + dx * Xr[16 + n];
        }
    }
    const size_t base = ((size_t)(b * 64 + c) * 32) * 512 + d;
    #pragma unroll
    for (int n = 0; n < 16; n++) summ[base + (size_t)n * 512] = __expf(A[n] * sdt);
    #pragma unroll
    for (int n = 0; n < 16; n++) summ[base + (size_t)(16 + n) * 512] = h[n];
}

// sequential combine over 64 chunks; overwrites p-slot with h_in (in-place)
__launch_bounds__(512)
__global__ void combine_k(float* __restrict__ summ)
{
    const int b = blockIdx.x >> 4, n = blockIdx.x & 15;
    const int d = threadIdx.x;
    float h = 0.f;
    for (int c = 0; c < 64; c++) {
        const size_t sb = ((size_t)((b * 64 + c) * 32 + n)) * 512 + d;
        const float p  = summ[sb];
        const float hl = summ[sb + 8192];
        summ[sb] = h;
        h = p * h + hl;
    }
}

// pass2: replay chunk from h_in; dt inline; writes y in-place over xc
__launch_bounds__(256)
__global__ void scan2_k(const float* __restrict__ xdbl, ushort* xc,
                        const ushort* __restrict__ dtw, const ushort* __restrict__ dtb,
                        const ushort* __restrict__ Alog, const float* __restrict__ summ,
                        const ushort* __restrict__ xz, const ushort* __restrict__ Dssm)
{
    __shared__ float XD[32 * 48];   // [step][col 0..47]: 0..15 dt, 16..31 B, 32..47 C
    const int tid = threadIdx.x;
    const int c = blockIdx.y, b = blockIdx.z;
    const int t0 = b * 2048 + c * 32;
    for (int e = tid; e < 1536; e += 256) {
        const size_t idx = (size_t)(t0 + (e / 48)) * 64 + (e % 48);
        XD[e] = xdbl[idx] + xdbl[idx + 524288];
    }
    __syncthreads();
    const int d = blockIdx.x * 256 + tid;

    const uint4 w0 = *(const uint4*)&dtw[d * 16];
    const uint4 w1 = *(const uint4*)&dtw[d * 16 + 8];
    const float wd[16] = { bflo(w0.x), bfhi(w0.x), bflo(w0.y), bfhi(w0.y),
                           bflo(w0.z), bfhi(w0.z), bflo(w0.w), bfhi(w0.w),
                           bflo(w1.x), bfhi(w1.x), bflo(w1.y), bfhi(w1.y),
                           bflo(w1.z), bfhi(w1.z), bflo(w1.w), bfhi(w1.w) };
    const float dtbv = bf2f(dtb[d]);

    float A[16], h[16];
    #pragma unroll
    for (int n = 0; n < 16; n++) A[n] = -__expf(bf2f(Alog[d * 16 + n]));
    const size_t base = ((size_t)(b * 64 + c) * 32) * 512 + d;
    #pragma unroll
    for (int n = 0; n < 16; n++) h[n] = summ[base + (size_t)n * 512];
    const float Dv = bf2f(Dssm[d]);

    for (int i = 0; i < 32; i++) {
        const int t = t0 + i;
        const float* Xr = &XD[i * 48];
        float s = dtbv;
        #pragma unroll
        for (int k = 0; k < 16; k++) s += Xr[k] * wd[k];
        const float dtv = (s > 15.f) ? s : __logf(1.f + __expf(s));
        const float xiv = bf2f(xc[(size_t)t * 512 + d]);
        const float dx = dtv * xiv;
        float yv = 0.f;
        #pragma unroll
        for (int n = 0; n < 16; n++) {
            const float da = __expf(dtv * A[n]);
            h[n] = da * h[n] + dx * Xr[16 + n];
            yv += h[n] * Xr[32 + n];
        }
        yv += xiv * Dv;
        const float zv = bf2f(xz[(size_t)t * 1024 + 512 + d]);
        yv *= zv / (1.f + __expf(-zv));
        xc[(size_t)t * 512 + d] = f2bf(yv);   // yb in-place
    }
}

// ---------------------------------------------------------------------------
// LayerNorms: one wave per token (4 tokens/block), 4 elems/lane, butterfly
// ---------------------------------------------------------------------------
__launch_bounds__(256)
__global__ void ln1_k(const void* __restrict__ xin, const float* __restrict__ sout,
                      const ushort* __restrict__ g, const ushort* __restrict__ bb,
                      float* __restrict__ y1f, ushort* __restrict__ y1b,
                      const ushort* __restrict__ sniffx)
{
    const int w = threadIdx.x >> 6, l = threadIdx.x & 63;
    const int t = blockIdx.x * 4 + w;
    const size_t base = (size_t)t * 256 + l * 4;
    const bool fl = sniff_inline(sniffx);
    float v[4];
    if (fl) {
        const uint2 xr = *(const uint2*)((const ushort*)xin + base);
        v[0] = bflo(xr.x); v[1] = bfhi(xr.x); v[2] = bflo(xr.y); v[3] = bfhi(xr.y);
    } else {
        const float4 xr = *(const float4*)((const float*)xin + base);
        v[0] = xr.x; v[1] = xr.y; v[2] = xr.z; v[3] = xr.w;
    }
    const float4 sv = *(const float4*)&sout[base];
    v[0] += sv.x; v[1] += sv.y; v[2] += sv.z; v[3] += sv.w;
    float s = v[0] + v[1] + v[2] + v[3];
    #pragma unroll
    for (int o = 32; o > 0; o >>= 1) s += __shfl_xor(s, o);
    const float mean = s * (1.f / 256.f);
    float q = 0.f;
    #pragma unroll
    for (int j = 0; j < 4; j++) { const float dv = v[j] - mean; q += dv * dv; }
    #pragma unroll
    for (int o = 32; o > 0; o >>= 1) q += __shfl_xor(q, o);
    const float r = rsqrtf(q * (1.f / 256.f) + 1e-5f);
    const uint2 gv = *(const uint2*)&g[l * 4];
    const uint2 bv = *(const uint2*)&bb[l * 4];
    const float gf[4] = { bflo(gv.x), bfhi(gv.x), bflo(gv.y), bfhi(gv.y) };
    const float bf[4] = { bflo(bv.x), bfhi(bv.x), bflo(bv.y), bfhi(bv.y) };
    float4 of;
    float* op = (float*)&of;
    ushort ob[4];
    #pragma unroll
    for (int j = 0; j < 4; j++) {
        const float o2 = (v[j] - mean) * r * gf[j] + bf[j];
        op[j] = o2; ob[j] = f2bf(o2);
    }
    *(float4*)&y1f[base] = of;
    *(uint2*)&y1b[base] = *(uint2*)&ob[0];
}

__launch_bounds__(256)
__global__ void ln2_k(const float* __restrict__ y1f, const float* __restrict__ ffn,
                      const ushort* __restrict__ g, const ushort* __restrict__ bb,
                      void* __restrict__ out, const ushort* __restrict__ sniffx)
{
    const int w = threadIdx.x >> 6, l = threadIdx.x & 63;
    const int t = blockIdx.x * 4 + w;
    const size_t base = (size_t)t * 256 + l * 4;
    const bool fl = sniff_inline(sniffx);
    const float4 av = *(const float4*)&y1f[base];
    const float4 fv = *(const float4*)&ffn[base];
    float v[4] = { av.x + fv.x, av.y + fv.y, av.z + fv.z, av.w + fv.w };
    float s = v[0] + v[1] + v[2] + v[3];
    #pragma unroll
    for (int o = 32; o > 0; o >>= 1) s += __shfl_xor(s, o);
    const float mean = s * (1.f / 256.f);
    float q = 0.f;
    #pragma unroll
    for (int j = 0; j < 4; j++) { const float dv = v[j] - mean; q += dv * dv; }
    #pragma unroll
    for (int o = 32; o > 0; o >>= 1) q += __shfl_xor(q, o);
    const float r = rsqrtf(q * (1.f / 256.f) + 1e-5f);
    const uint2 gv = *(const uint2*)&g[l * 4];
    const uint2 bv = *(const uint2*)&bb[l * 4];
    const float gf[4] = { bflo(gv.x), bfhi(gv.x), bflo(gv.y), bfhi(gv.y) };
    const float bf[4] = { bflo(bv.x), bfhi(bv.x), bflo(bv.y), bfhi(bv.y) };
    if (fl) {
        ushort ob[4];
        #pragma unroll
        for (int j = 0; j < 4; j++) ob[j] = f2bf((v[j] - mean) * r * gf[j] + bf[j]);
        *(uint2*)((ushort*)out + base) = *(uint2*)&ob[0];
    } else {
        float4 of;
        float* op = (float*)&of;
        #pragma unroll
        for (int j = 0; j < 4; j++) op[j] = (v[j] - mean) * r * gf[j] + bf[j];
        *(float4*)((float*)out + base) = of;
    }
}

// ---------------------------------------------------------------------------
extern "C" void kernel_launch(void* const* d_in, const int* in_sizes, int n_in,
                              void* d_out, int out_size, void* d_ws, size_t ws_size,
                              hipStream_t stream)
{
    char* ws = (char*)d_ws;
    ushort* canon = (ushort*)(ws + 256);

    static const int coff[20] = {
        0,        2097152,  2359296,  2360320,  2362368,
        2362880,  2387456,  2395648,  2396160,  2404352,
        2404864,  2535936,  2536192,  2536448,  2536704,
        2798848,  2799872,  3062016,  3062272,  3062528 };
    static const int ctot = 3062784;

    CanonArgs ca;
    for (int i = 0; i < 20; i++) { ca.src[i] = d_in[i]; ca.off[i] = coff[i]; }
    ca.total = ctot;

    const ushort* cx   = canon + coff[0];
    const ushort* cipw = canon + coff[1];
    const ushort* cipb = canon + coff[2];
    const ushort* ccw  = canon + coff[3];
    const ushort* ccb  = canon + coff[4];
    const ushort* cdtw = canon + coff[6];
    const ushort* cdtb = canon + coff[7];
    const ushort* calog= canon + coff[8];
    const ushort* cdssm= canon + coff[9];
    const ushort* copw = canon + coff[10];
    const ushort* copb = canon + coff[11];
    const ushort* cln1g= canon + coff[12];
    const ushort* cln1b= canon + coff[13];
    const ushort* cf1w = canon + coff[14];
    const ushort* cf1b = canon + coff[15];
    const ushort* cf2w = canon + coff[16];
    const ushort* cf2b = canon + coff[17];
    const ushort* cln2g= canon + coff[18];
    const ushort* cln2b= canon + coff[19];

    ushort* xpw_pad = (ushort*)(ws + 6291456);  // [64,512] bf16
    ushort* xz      = (ushort*)(ws + 8388608);  // [8192,1024] bf16, 16 MB
    ushort* xc      = (ushort*)(ws + 25165824); // [8192,512] bf16 (yb in-place later)
    float*  xdbl    = (float*)(ws + 33554432);  // 2 x [8192,64] f32 split-K halves, 4 MB
    float*  summ    = (float*)(ws + 37748736);  // [4,64,32,512] f32, 16 MB
    float*  sout    = (float*)(ws + 53477376);  // [8192,256] f32, 8 MB
    float*  y1f     = (float*)(ws + 61865984);  // [8192,256] f32, 8 MB
    ushort* y1b     = (ushort*)(ws + 70254592); // [8192,256] bf16, 4 MB
    ushort* f1      = (ushort*)(ws + 74448896); // [8192,1024] bf16, 16 MB
    float*  ffn     = (float*)(ws + 91226112);  // [8192,256] f32, 8 MB
    ushort* yb      = xc;
    const ushort* sx = (const ushort*)d_in[0];

    // 1. canon + xpw padding (inline sniff)
    canon_k<<<(ctot + 8192 + 255) / 256, 256, 0, stream>>>(ca, canon, xpw_pad, sx);
    // 2. in_proj: xz = x @ ipw^T + ipb
    gemm_bt<128, 128, 0, true, false, true><<<dim3(64, 8), 256, 0, stream>>>(
        cx, cipw, cipb, nullptr, xz, 8192, 1024, 256, 256);
    // 3. conv + silu -> xc
    conv_silu_k<<<2048, 256, 0, stream>>>(xz, ccw, ccb, xc);
    // 4. xdbl = xc @ xpw_pad^T  (split-K, 2 halves)
    xdbl_k<<<dim3(128, 2), 256, 0, stream>>>(xc, xpw_pad, xdbl);
    // 5-7. chunked scan (dt inline)
    scan1_k<<<dim3(2, 64, 4), 256, 0, stream>>>(xdbl, xc, cdtw, cdtb, calog, summ);
    combine_k<<<64, 512, 0, stream>>>(summ);
    scan2_k<<<dim3(2, 64, 4), 256, 0, stream>>>(xdbl, xc, cdtw, cdtb, calog, summ, xz, cdssm);
    // 8. out_proj -> sout (f32)
    gemm_bt<128, 64, 0, true, true, false><<<dim3(64, 4), 256, 0, stream>>>(
        yb, copw, copb, sout, nullptr, 8192, 256, 512, 512);
    // 9. y1 = LN(x + sout)
    ln1_k<<<2048, 256, 0, stream>>>(d_in[0], sout, cln1g, cln1b, y1f, y1b, sx);
    // 10. fc1 + gelu -> f1
    gemm_bt<128, 128, 1, true, false, true><<<dim3(64, 8), 256, 0, stream>>>(
        y1b, cf1w, cf1b, nullptr, f1, 8192, 1024, 256, 256);
    // 11. fc2 + gelu -> ffn (f32)
    gemm_bt<128, 64, 1, true, true, false><<<dim3(64, 4), 256, 0, stream>>>(
        f1, cf2w, cf2b, ffn, nullptr, 8192, 256, 1024, 1024);
    // 12. out = LN(y1 + ffn)
    ln2_k<<<2048, 256, 0, stream>>>(y1f, ffn, cln2g, cln2b, d_out, sx);
}